// Round 17
// baseline (194.773 us; speedup 1.0000x reference)
//
#include <hip/hip_runtime.h>
#include <hip/hip_bf16.h>

#define DEVI __device__ __forceinline__

typedef __attribute__((ext_vector_type(8))) short short8v;
typedef __attribute__((ext_vector_type(4))) float f32x4;
typedef __attribute__((ext_vector_type(16))) float f32x16;
typedef __attribute__((ext_vector_type(2))) unsigned u32x2;
typedef __attribute__((ext_vector_type(4))) unsigned u32x4;

DEVI short f2bf(float f) {
  __hip_bfloat16 h = __float2bfloat16(f);
  return __builtin_bit_cast(short, h);
}
DEVI float bf2f(short s) {
  unsigned u = ((unsigned)(unsigned short)s) << 16;
  return __builtin_bit_cast(float, u);
}
DEVI unsigned packbf(float a, float b) {
  return (unsigned)(unsigned short)f2bf(a) | ((unsigned)(unsigned short)f2bf(b) << 16);
}
DEVI void gload16(const void* g, void* l) {
  __builtin_amdgcn_global_load_lds((const __attribute__((address_space(1))) void*)g,
                                   (__attribute__((address_space(3))) void*)l, 16, 0, 0);
}
#define MFMA16(a, b, c) __builtin_amdgcn_mfma_f32_16x16x32_bf16((a), (b), (c), 0, 0, 0)
#define MFMA32(a, b, c) __builtin_amdgcn_mfma_f32_32x32x16_bf16((a), (b), (c), 0, 0, 0)
#define PLSWAP(a, b) asm("v_permlane32_swap_b32 %0, %1" : "+v"(a), "+v"(b))

// ---------------- prep kernels ----------------

__global__ void cvt_all(const float* __restrict__ x, const float* __restrict__ wq,
                        const float* __restrict__ wo, short* __restrict__ xb,
                        short* __restrict__ wqb, short* __restrict__ wob) {
  int i = blockIdx.x * blockDim.x + threadIdx.x;
  const float* in;
  short* out;
  if (i < 2097152) { in = x; out = xb; }
  else if (i < 2097152 + 786432) { in = wq; out = wqb; i -= 2097152; }
  else { in = wo; out = wob; i -= 2097152 + 786432; }
  float4 v = ((const float4*)in)[i];
  short4 o;
  o.x = f2bf(v.x); o.y = f2bf(v.y); o.z = f2bf(v.z); o.w = f2bf(v.w);
  ((short4*)out)[i] = o;
}

__global__ void rope_table(float2* __restrict__ tbl) {
  int i = blockIdx.x * blockDim.x + threadIdx.x;  // 2048*32
  int n = i >> 5, f = i & 31;
  float inv = powf(10000.0f, -(float)f * (1.0f / 32.0f));
  float ang = (float)n * inv;
  tbl[i] = make_float2(cosf(ang), sinf(ang));
}

__global__ void rope_k(short* __restrict__ kk, const float2* __restrict__ tbl) {
  int i = blockIdx.x * blockDim.x + threadIdx.x;  // 16B chunks
  int row = i >> 3, c8 = i & 7;
  int n = row & 2047;
  short* ad = kk + (size_t)row * 64 + c8 * 8;
  short8v vv = *(short8v*)ad;
  short8v ov;
#pragma unroll
  for (int j = 0; j < 4; ++j) {
    float2 cs = tbl[n * 32 + c8 * 4 + j];
    float x0 = bf2f(vv[2 * j]), x1 = bf2f(vv[2 * j + 1]);
    ov[2 * j]     = f2bf(x0 * cs.x - x1 * cs.y);
    ov[2 * j + 1] = f2bf(x0 * cs.y + x1 * cs.x);
  }
  *(short8v*)ad = ov;
}

// ---------------- GEMM1: 256x256 tile, 8 waves, BK=64 (r13/r15 config) ----
__global__ __launch_bounds__(512, 2)
void gemm256(const short* __restrict__ A, const short* __restrict__ Bw,
             const float* __restrict__ bias,
             short* __restrict__ q, short* __restrict__ k, short* __restrict__ v,
             int Kdim) {
  __shared__ __attribute__((aligned(16))) short lds[65536];  // 128 KB
  const int t = threadIdx.x;            // 0..511
  const int lane = t & 63, w = t >> 6;  // 8 waves
  const int wr = w >> 2, wc = w & 3;    // 2M x 4N
  const int g = lane >> 4, r16 = lane & 15;
  const int n0 = blockIdx.x * 256, m0 = blockIdx.y * 256;

  int goffs[4], loffs[4];
#pragma unroll
  for (int p = 0; p < 4; ++p) {
    int c = p * 512 + t;
    int row = c >> 3, u = c & 7;
    goffs[p] = row * Kdim + ((u ^ (row & 7)) * 8);
    loffs[p] = c * 16;
  }
  const short* Abase = A + (size_t)m0 * Kdim;
  const short* Bbase = Bw + (size_t)n0 * Kdim;

  auto STAGE = [&](int s, int k0) {
#pragma unroll
    for (int p = 0; p < 4; ++p) {
      gload16(Abase + k0 + goffs[p], (char*)lds + s * 32768 + loffs[p]);
      gload16(Bbase + k0 + goffs[p], (char*)lds + 65536 + s * 32768 + loffs[p]);
    }
  };

  f32x4 acc[8][4];
#pragma unroll
  for (int i = 0; i < 8; ++i)
#pragma unroll
    for (int j = 0; j < 4; ++j) acc[i][j] = (f32x4){0.f, 0.f, 0.f, 0.f};

  const int nsteps = Kdim >> 6;  // 16
  STAGE(0, 0);
  __syncthreads();

  int cur = 0;
  for (int st = 0; st < nsteps; ++st) {
    if (st + 1 < nsteps) STAGE(cur ^ 1, (st + 1) << 6);
    const char* Ab = (const char*)lds + cur * 32768;
    const char* Bb = (const char*)lds + 65536 + cur * 32768;
#pragma unroll
    for (int ks = 0; ks < 2; ++ks) {
      short8v bf[4];
#pragma unroll
      for (int ni = 0; ni < 4; ++ni) {
        int rowb = wc * 64 + ni * 16 + r16;
        bf[ni] = *(const short8v*)(Bb + rowb * 128 + (((ks * 4 + g) ^ (rowb & 7)) << 4));
      }
#pragma unroll
      for (int mi = 0; mi < 8; ++mi) {
        int rowa = wr * 128 + mi * 16 + r16;
        short8v af =
            *(const short8v*)(Ab + rowa * 128 + (((ks * 4 + g) ^ (rowa & 7)) << 4));
#pragma unroll
        for (int ni = 0; ni < 4; ++ni)
          acc[mi][ni] = MFMA16(af, bf[ni], acc[mi][ni]);
      }
    }
    __syncthreads();
    cur ^= 1;
  }

  const int b = m0 >> 11, nb = m0 & 2047;
  if (n0 < 2048) {
#pragma unroll
    for (int ni = 0; ni < 4; ++ni) {
      int col = n0 + wc * 64 + ni * 16 + r16;
      float bv = bias[col];
      int s = col >> 10, h = (col & 1023) >> 6, d = col & 63;
      short* dst = (s == 0) ? q : k;
#pragma unroll
      for (int mi = 0; mi < 8; ++mi) {
        int mrow = m0 + wr * 128 + mi * 16 + g * 4;
#pragma unroll
        for (int r = 0; r < 4; ++r) {
          int n = (mrow + r) & 2047;
          dst[(((size_t)(b * 16 + h)) * 2048 + n) * 64 + d] = f2bf(acc[mi][ni][r] + bv);
        }
      }
    }
  } else {
    short* Cs = lds;  // [64][264]
    const int hdrb = (n0 - 2048) >> 6;
#pragma unroll
    for (int hh = 0; hh < 4; ++hh) {
      if (wc == hh) {
#pragma unroll
        for (int ni = 0; ni < 4; ++ni) {
          float bv = bias[n0 + hh * 64 + ni * 16 + r16];
#pragma unroll
          for (int mi = 0; mi < 8; ++mi) {
            u32x2 pk;
            pk[0] = packbf(acc[mi][ni][0] + bv, acc[mi][ni][1] + bv);
            pk[1] = packbf(acc[mi][ni][2] + bv, acc[mi][ni][3] + bv);
            *(u32x2*)&Cs[(ni * 16 + r16) * 264 + wr * 128 + mi * 16 + g * 4] = pk;
          }
        }
      }
      __syncthreads();
      short* vdst = v + ((size_t)(b * 16 + hdrb + hh)) * 64 * 2048;
#pragma unroll
      for (int j = 0; j < 4; ++j) {
        int chunk = j * 512 + t;
        int d = chunk >> 5, c = chunk & 31;
        short8v val = *(const short8v*)&Cs[d * 264 + c * 8];
        *(short8v*)(vdst + (size_t)d * 2048 + nb + c * 8) = val;
      }
      __syncthreads();
    }
  }
}

// ---------------- GEMM2: 128x128, f32 out (unchanged) ----------
__global__ __launch_bounds__(256)
void gemm_f32(const short* __restrict__ A, const short* __restrict__ Bw,
              const float* __restrict__ bias, float* __restrict__ fout,
              int Ndim, int Kdim) {
  __shared__ __attribute__((aligned(16))) short As[3][128 * 32];
  __shared__ __attribute__((aligned(16))) short Bs[3][128 * 32];
  const int t = threadIdx.x;
  const int lane = t & 63, w = t >> 6;
  const int wr = w >> 1, wc = w & 1;
  const int g = lane >> 4, r16 = lane & 15;
  const int m0 = blockIdx.y * 128, n0 = blockIdx.x * 128;

  int goffs[2], loffs[2];
#pragma unroll
  for (int p = 0; p < 2; ++p) {
    int c = p * 256 + t;
    int row = c >> 2, u = c & 3;
    goffs[p] = row * Kdim + ((u ^ ((row >> 1) & 3)) * 8);
    loffs[p] = c * 16;
  }
  const short* Abase = A + (size_t)m0 * Kdim;
  const short* Bbase = Bw + (size_t)n0 * Kdim;

  auto STAGE = [&](int s, int k0) {
#pragma unroll
    for (int p = 0; p < 2; ++p) {
      gload16(Abase + k0 + goffs[p], (char*)&As[s][0] + loffs[p]);
      gload16(Bbase + k0 + goffs[p], (char*)&Bs[s][0] + loffs[p]);
    }
  };

  f32x4 acc[4][4];
#pragma unroll
  for (int i = 0; i < 4; ++i)
#pragma unroll
    for (int j = 0; j < 4; ++j) acc[i][j] = (f32x4){0.f, 0.f, 0.f, 0.f};

  const int nsteps = Kdim >> 5;
  STAGE(0, 0);
  STAGE(1, 32);
  asm volatile("s_waitcnt vmcnt(4)" ::: "memory");
  __builtin_amdgcn_s_barrier();
  asm volatile("" ::: "memory");

  int cur = 0, pre = 2;
  const int rsw = (r16 >> 1) & 3;
  for (int st = 0; st < nsteps; ++st) {
    if (st + 2 < nsteps) STAGE(pre, (st + 2) << 5);
    short8v af[4], bf[4];
#pragma unroll
    for (int mi = 0; mi < 4; ++mi)
      af[mi] = *(const short8v*)&As[cur][(wr * 64 + mi * 16 + r16) * 32 +
                                         ((g ^ rsw) * 8)];
#pragma unroll
    for (int ni = 0; ni < 4; ++ni)
      bf[ni] = *(const short8v*)&Bs[cur][(wc * 64 + ni * 16 + r16) * 32 +
                                         ((g ^ rsw) * 8)];
#pragma unroll
    for (int mi = 0; mi < 4; ++mi)
#pragma unroll
      for (int ni = 0; ni < 4; ++ni)
        acc[mi][ni] = MFMA16(af[mi], bf[ni], acc[mi][ni]);
    if (st + 2 < nsteps) asm volatile("s_waitcnt vmcnt(4)" ::: "memory");
    else                 asm volatile("s_waitcnt vmcnt(0)" ::: "memory");
    __builtin_amdgcn_s_barrier();
    asm volatile("" ::: "memory");
    cur = (cur == 2) ? 0 : cur + 1;
    pre = (pre == 2) ? 0 : pre + 1;
  }

#pragma unroll
  for (int ni = 0; ni < 4; ++ni) {
    int col = n0 + wc * 64 + ni * 16 + r16;
    float bv = bias[col];
#pragma unroll
    for (int mi = 0; mi < 4; ++mi) {
      int mrow = m0 + wr * 64 + mi * 16 + g * 4;
#pragma unroll
      for (int r = 0; r < 4; ++r)
        fout[(size_t)(mrow + r) * Ndim + col] = acc[mi][ni][r] + bv;
    }
  }
}

// ---------------- causal flash attention (v5.1: 4-wave blocks) ------------
// Inner code identical to v5 (32x32 MFMA, in-register P via permlane32_swap,
// static-M softmax). Decomposition: 4 waves x 32 q-rows = 128 q-rows/block,
// 1024 blocks -> ~3 blocks/CU co-resident (v5's 512-thread blocks were
// 1 block/CU: latency/barrier-bound, pipes <30% busy). Heavy-first pairing.
__global__ __launch_bounds__(256)
void fattn(const short* __restrict__ q, const short* __restrict__ k,
           const short* __restrict__ vT, const float2* __restrict__ tbl,
           short* __restrict__ o) {
  const int bx = blockIdx.x;
  const int idx = bx >> 6;
  const int qt = (idx < 8) ? (15 - idx) : (idx - 8);  // pairs sum to 15
  const int bh = bx & 63;
  const int b = bh >> 4, h = bh & 15;
  const int t = threadIdx.x, lane = t & 63, w = t >> 6;
  const int q32 = lane & 31, hi = lane >> 5;
  const int hi4 = hi * 4;

  __shared__ __attribute__((aligned(16))) short Ks[2][64 * 64];
  __shared__ __attribute__((aligned(16))) short Vt[2][64 * 64];

  const short* qb = q + (size_t)bh * 2048 * 64;
  const short* kb = k + (size_t)bh * 2048 * 64;
  const short* vb = vT + (size_t)bh * 2048 * 64;

  // staging: 512 chunks per operand, 2 per thread
  int koff[2], voff[2], loff[2];
#pragma unroll
  for (int p = 0; p < 2; ++p) {
    int c = p * 256 + t;
    int row = c >> 3, u = c & 7;
    int x8 = (u ^ (row & 7)) * 8;
    koff[p] = row * 64 + x8;
    voff[p] = row * 2048 + x8;
    loff[p] = c * 16;
  }
  auto STAGE = [&](int s, int kt) {
#pragma unroll
    for (int p = 0; p < 2; ++p) {
      gload16(kb + (size_t)kt * 4096 + koff[p], (char*)&Ks[s][0] + loff[p]);
      gload16(vb + kt * 64 + voff[p], (char*)&Vt[s][0] + loff[p]);
    }
  };

  const int q0w = qt * 128 + w * 32;
  const int nrow = q0w + q32;

  // Q B-frags: lane holds Q[nrow][d = ds*16 + hi*8 .. +7]; RoPE+scale fused
  const float sc = 0.125f * 1.44269504088896f;
  short8v aq[4];
#pragma unroll
  for (int ds = 0; ds < 4; ++ds) {
    short8v raw = *(const short8v*)(qb + (size_t)nrow * 64 + ds * 16 + hi * 8);
    short8v rq;
#pragma unroll
    for (int j = 0; j < 4; ++j) {
      float2 cs = tbl[nrow * 32 + ds * 8 + hi4 + j];
      float x0 = bf2f(raw[2 * j]), x1 = bf2f(raw[2 * j + 1]);
      rq[2 * j]     = f2bf((x0 * cs.x - x1 * cs.y) * sc);
      rq[2 * j + 1] = f2bf((x0 * cs.y + x1 * cs.x) * sc);
    }
    aq[ds] = rq;
  }

  const short one_bf = 0x3F80;
  const short8v ones = {one_bf, one_bf, one_bf, one_bf, one_bf, one_bf, one_bf, one_bf};
  const float M = 24.0f;

  f32x16 oacc[2], lacc;
#pragma unroll
  for (int j = 0; j < 16; ++j) { oacc[0][j] = 0.f; oacc[1][j] = 0.f; lacc[j] = 0.f; }

  const int ktmax = 2 * qt + 1;

  STAGE(0, 0);
  __syncthreads();

  for (int kt = 0; kt <= ktmax; ++kt) {
    const int cur = kt & 1;
    if (kt < ktmax) STAGE(cur ^ 1, kt + 1);

    if (kt * 64 <= q0w + 31) {
      // ---- QK^T: S^T[key][q], A = K rows, B = Q ----
      f32x16 s[2];
#pragma unroll
      for (int j = 0; j < 16; ++j) { s[0][j] = 0.f; s[1][j] = 0.f; }
      __builtin_amdgcn_s_setprio(1);
#pragma unroll
      for (int ds = 0; ds < 4; ++ds) {
        int u = 2 * ds + hi;
#pragma unroll
        for (int kbl = 0; kbl < 2; ++kbl) {
          int key = kbl * 32 + q32;
          short8v kf = *(const short8v*)((const char*)&Ks[cur][0] + key * 128 +
                                         ((u ^ (key & 7)) << 4));
          s[kbl] = MFMA32(kf, aq[ds], s[kbl]);
        }
      }
      __builtin_amdgcn_s_setprio(0);

      // ---- static-M softmax + pack + permlane redistribution ----
      const bool needmask = (kt * 64 + 63 > q0w);
      unsigned pa[4][4];
#pragma unroll
      for (int kbl = 0; kbl < 2; ++kbl) {
        if (needmask) {
#pragma unroll
          for (int r = 0; r < 16; ++r) {
            int keyg = kt * 64 + kbl * 32 + (r & 3) + 8 * (r >> 2) + hi4;
            if (keyg > nrow) s[kbl][r] = -1e30f;
          }
        }
        unsigned pk[8];
#pragma unroll
        for (int p = 0; p < 8; ++p) {
          float p0 = __builtin_amdgcn_exp2f(s[kbl][2 * p] - M);
          float p1 = __builtin_amdgcn_exp2f(s[kbl][2 * p + 1] - M);
          pk[p] = packbf(p0, p1);
        }
        {
          unsigned x0 = pk[0], x1 = pk[2];
          unsigned y0 = pk[1], y1 = pk[3];
          PLSWAP(x0, x1);
          PLSWAP(y0, y1);
          pa[kbl * 2][0] = x0; pa[kbl * 2][1] = y0;
          pa[kbl * 2][2] = x1; pa[kbl * 2][3] = y1;
        }
        {
          unsigned x0 = pk[4], x1 = pk[6];
          unsigned y0 = pk[5], y1 = pk[7];
          PLSWAP(x0, x1);
          PLSWAP(y0, y1);
          pa[kbl * 2 + 1][0] = x0; pa[kbl * 2 + 1][1] = y0;
          pa[kbl * 2 + 1][2] = x1; pa[kbl * 2 + 1][3] = y1;
        }
      }

      // ---- PV + rowsum ----
      __builtin_amdgcn_s_setprio(1);
#pragma unroll
      for (int kk = 0; kk < 4; ++kk) {
        short8v paf = __builtin_bit_cast(
            short8v, (u32x4){pa[kk][0], pa[kk][1], pa[kk][2], pa[kk][3]});
        lacc = MFMA32(paf, ones, lacc);
        int u = 2 * kk + hi;
#pragma unroll
        for (int db = 0; db < 2; ++db) {
          int d = db * 32 + q32;
          short8v vf = *(const short8v*)((const char*)&Vt[cur][0] + d * 128 +
                                         ((u ^ (d & 7)) << 4));
          oacc[db] = MFMA32(paf, vf, oacc[db]);
        }
      }
      __builtin_amdgcn_s_setprio(0);
    }
    __syncthreads();
  }

  // epilogue: row q = q0w + crow(r,hi); col d = db*32 + q32
#pragma unroll
  for (int r = 0; r < 16; ++r) {
    float ilr = 1.f / lacc[r];
    int qg = q0w + (r & 3) + 8 * (r >> 2) + hi4;
    short* orow = o + ((size_t)(b * 2048 + qg)) * 1024 + h * 64;
    orow[q32]      = f2bf(oacc[0][r] * ilr);
    orow[32 + q32] = f2bf(oacc[1][r] * ilr);
  }
}

// ---------------- launcher ----------------
extern "C" void kernel_launch(void* const* d_in, const int* in_sizes, int n_in,
                              void* d_out, int out_size, void* d_ws, size_t ws_size,
                              hipStream_t stream) {
  const float* x    = (const float*)d_in[0];
  const float* Wqkv = (const float*)d_in[1];
  const float* bqkv = (const float*)d_in[2];
  const float* Wout = (const float*)d_in[3];
  const float* bout = (const float*)d_in[4];

  char* p = (char*)d_ws;
  short* xb = (short*)p;    p += (size_t)8192 * 1024 * 2;   // x bf16; reused as attn output
  short* wqkvb = (short*)p; p += (size_t)3072 * 1024 * 2;
  short* woutb = (short*)p; p += (size_t)1024 * 1024 * 2;
  short* qbf = (short*)p;   p += (size_t)64 * 2048 * 64 * 2;
  short* kbf = (short*)p;   p += (size_t)64 * 2048 * 64 * 2;
  short* vbf = (short*)p;   p += (size_t)64 * 2048 * 64 * 2;  // vT (BH, D, N)
  float2* tbl = (float2*)p; p += (size_t)2048 * 32 * 8;

  cvt_all<<<12288, 256, 0, stream>>>(x, Wqkv, Wout, xb, wqkvb, woutb);
  rope_table<<<256, 256, 0, stream>>>(tbl);

  gemm256<<<dim3(12, 32), 512, 0, stream>>>(xb, wqkvb, bqkv, qbf, kbf, vbf, 1024);
  rope_k<<<4096, 256, 0, stream>>>(kbf, tbl);
  fattn<<<dim3(1024), 256, 0, stream>>>(qbf, kbf, vbf, tbl, xb);
  gemm_f32<<<dim3(8, 64), 256, 0, stream>>>(xb, woutb, bout, (float*)d_out, 1024, 1024);
}

// Round 18
// 182.451 us; speedup vs baseline: 1.0675x; 1.0675x over previous
//
#include <hip/hip_runtime.h>
#include <hip/hip_bf16.h>

#define DEVI __device__ __forceinline__

typedef __attribute__((ext_vector_type(8))) short short8v;
typedef __attribute__((ext_vector_type(4))) float f32x4;
typedef __attribute__((ext_vector_type(16))) float f32x16;
typedef __attribute__((ext_vector_type(2))) unsigned u32x2;
typedef __attribute__((ext_vector_type(4))) unsigned u32x4;

DEVI short f2bf(float f) {
  __hip_bfloat16 h = __float2bfloat16(f);
  return __builtin_bit_cast(short, h);
}
DEVI float bf2f(short s) {
  unsigned u = ((unsigned)(unsigned short)s) << 16;
  return __builtin_bit_cast(float, u);
}
DEVI unsigned packbf(float a, float b) {
  return (unsigned)(unsigned short)f2bf(a) | ((unsigned)(unsigned short)f2bf(b) << 16);
}
DEVI void gload16(const void* g, void* l) {
  __builtin_amdgcn_global_load_lds((const __attribute__((address_space(1))) void*)g,
                                   (__attribute__((address_space(3))) void*)l, 16, 0, 0);
}
#define MFMA16(a, b, c) __builtin_amdgcn_mfma_f32_16x16x32_bf16((a), (b), (c), 0, 0, 0)
#define MFMA32(a, b, c) __builtin_amdgcn_mfma_f32_32x32x16_bf16((a), (b), (c), 0, 0, 0)
#define PLSWAP(a, b) asm("v_permlane32_swap_b32 %0, %1" : "+v"(a), "+v"(b))

// ---------------- prep kernels ----------------

__global__ void cvt_all(const float* __restrict__ x, const float* __restrict__ wq,
                        const float* __restrict__ wo, short* __restrict__ xb,
                        short* __restrict__ wqb, short* __restrict__ wob) {
  int i = blockIdx.x * blockDim.x + threadIdx.x;
  const float* in;
  short* out;
  if (i < 2097152) { in = x; out = xb; }
  else if (i < 2097152 + 786432) { in = wq; out = wqb; i -= 2097152; }
  else { in = wo; out = wob; i -= 2097152 + 786432; }
  float4 v = ((const float4*)in)[i];
  short4 o;
  o.x = f2bf(v.x); o.y = f2bf(v.y); o.z = f2bf(v.z); o.w = f2bf(v.w);
  ((short4*)out)[i] = o;
}

__global__ void rope_table(float2* __restrict__ tbl) {
  int i = blockIdx.x * blockDim.x + threadIdx.x;  // 2048*32
  int n = i >> 5, f = i & 31;
  float inv = powf(10000.0f, -(float)f * (1.0f / 32.0f));
  float ang = (float)n * inv;
  tbl[i] = make_float2(cosf(ang), sinf(ang));
}

__global__ void rope_k(short* __restrict__ kk, const float2* __restrict__ tbl) {
  int i = blockIdx.x * blockDim.x + threadIdx.x;  // 16B chunks
  int row = i >> 3, c8 = i & 7;
  int n = row & 2047;
  short* ad = kk + (size_t)row * 64 + c8 * 8;
  short8v vv = *(short8v*)ad;
  short8v ov;
#pragma unroll
  for (int j = 0; j < 4; ++j) {
    float2 cs = tbl[n * 32 + c8 * 4 + j];
    float x0 = bf2f(vv[2 * j]), x1 = bf2f(vv[2 * j + 1]);
    ov[2 * j]     = f2bf(x0 * cs.x - x1 * cs.y);
    ov[2 * j + 1] = f2bf(x0 * cs.y + x1 * cs.x);
  }
  *(short8v*)ad = ov;
}

// ---------------- GEMM1: 256x256 tile, 8 waves, BK=64 (r15-exact) ---------
// + T1 chunked XCD swizzle: 384 blocks % 8 == 0, each XCD gets 48 contiguous
// tiles (4 full M-rows): A-panel reuse x12, B-panel x4 within one L2.
__global__ __launch_bounds__(512, 2)
void gemm256(const short* __restrict__ A, const short* __restrict__ Bw,
             const float* __restrict__ bias,
             short* __restrict__ q, short* __restrict__ k, short* __restrict__ v,
             int Kdim) {
  __shared__ __attribute__((aligned(16))) short lds[65536];  // 128 KB
  const int t = threadIdx.x;            // 0..511
  const int lane = t & 63, w = t >> 6;  // 8 waves
  const int wr = w >> 2, wc = w & 3;    // 2M x 4N
  const int g = lane >> 4, r16 = lane & 15;

  // XCD-chunked block swizzle (bijective: 384 % 8 == 0; 48 blocks per XCD)
  const int flat = blockIdx.y * 12 + blockIdx.x;
  const int swz = (flat & 7) * 48 + (flat >> 3);
  const int n0 = (swz % 12) * 256, m0 = (swz / 12) * 256;

  int goffs[4], loffs[4];
#pragma unroll
  for (int p = 0; p < 4; ++p) {
    int c = p * 512 + t;
    int row = c >> 3, u = c & 7;
    goffs[p] = row * Kdim + ((u ^ (row & 7)) * 8);
    loffs[p] = c * 16;
  }
  const short* Abase = A + (size_t)m0 * Kdim;
  const short* Bbase = Bw + (size_t)n0 * Kdim;

  auto STAGE = [&](int s, int k0) {
#pragma unroll
    for (int p = 0; p < 4; ++p) {
      gload16(Abase + k0 + goffs[p], (char*)lds + s * 32768 + loffs[p]);
      gload16(Bbase + k0 + goffs[p], (char*)lds + 65536 + s * 32768 + loffs[p]);
    }
  };

  f32x4 acc[8][4];
#pragma unroll
  for (int i = 0; i < 8; ++i)
#pragma unroll
    for (int j = 0; j < 4; ++j) acc[i][j] = (f32x4){0.f, 0.f, 0.f, 0.f};

  const int nsteps = Kdim >> 6;  // 16
  STAGE(0, 0);
  __syncthreads();

  int cur = 0;
  for (int st = 0; st < nsteps; ++st) {
    if (st + 1 < nsteps) STAGE(cur ^ 1, (st + 1) << 6);
    const char* Ab = (const char*)lds + cur * 32768;
    const char* Bb = (const char*)lds + 65536 + cur * 32768;
#pragma unroll
    for (int ks = 0; ks < 2; ++ks) {
      short8v bf[4];
#pragma unroll
      for (int ni = 0; ni < 4; ++ni) {
        int rowb = wc * 64 + ni * 16 + r16;
        bf[ni] = *(const short8v*)(Bb + rowb * 128 + (((ks * 4 + g) ^ (rowb & 7)) << 4));
      }
#pragma unroll
      for (int mi = 0; mi < 8; ++mi) {
        int rowa = wr * 128 + mi * 16 + r16;
        short8v af =
            *(const short8v*)(Ab + rowa * 128 + (((ks * 4 + g) ^ (rowa & 7)) << 4));
#pragma unroll
        for (int ni = 0; ni < 4; ++ni)
          acc[mi][ni] = MFMA16(af, bf[ni], acc[mi][ni]);
      }
    }
    __syncthreads();
    cur ^= 1;
  }

  const int b = m0 >> 11, nb = m0 & 2047;
  if (n0 < 2048) {
#pragma unroll
    for (int ni = 0; ni < 4; ++ni) {
      int col = n0 + wc * 64 + ni * 16 + r16;
      float bv = bias[col];
      int s = col >> 10, h = (col & 1023) >> 6, d = col & 63;
      short* dst = (s == 0) ? q : k;
#pragma unroll
      for (int mi = 0; mi < 8; ++mi) {
        int mrow = m0 + wr * 128 + mi * 16 + g * 4;
#pragma unroll
        for (int r = 0; r < 4; ++r) {
          int n = (mrow + r) & 2047;
          dst[(((size_t)(b * 16 + h)) * 2048 + n) * 64 + d] = f2bf(acc[mi][ni][r] + bv);
        }
      }
    }
  } else {
    short* Cs = lds;  // [64][264]
    const int hdrb = (n0 - 2048) >> 6;
#pragma unroll
    for (int hh = 0; hh < 4; ++hh) {
      if (wc == hh) {
#pragma unroll
        for (int ni = 0; ni < 4; ++ni) {
          float bv = bias[n0 + hh * 64 + ni * 16 + r16];
#pragma unroll
          for (int mi = 0; mi < 8; ++mi) {
            u32x2 pk;
            pk[0] = packbf(acc[mi][ni][0] + bv, acc[mi][ni][1] + bv);
            pk[1] = packbf(acc[mi][ni][2] + bv, acc[mi][ni][3] + bv);
            *(u32x2*)&Cs[(ni * 16 + r16) * 264 + wr * 128 + mi * 16 + g * 4] = pk;
          }
        }
      }
      __syncthreads();
      short* vdst = v + ((size_t)(b * 16 + hdrb + hh)) * 64 * 2048;
#pragma unroll
      for (int j = 0; j < 4; ++j) {
        int chunk = j * 512 + t;
        int d = chunk >> 5, c = chunk & 31;
        short8v val = *(const short8v*)&Cs[d * 264 + c * 8];
        *(short8v*)(vdst + (size_t)d * 2048 + nb + c * 8) = val;
      }
      __syncthreads();
    }
  }
}

// ---------------- GEMM2: 128x128, f32 out (unchanged) ----------
__global__ __launch_bounds__(256)
void gemm_f32(const short* __restrict__ A, const short* __restrict__ Bw,
              const float* __restrict__ bias, float* __restrict__ fout,
              int Ndim, int Kdim) {
  __shared__ __attribute__((aligned(16))) short As[3][128 * 32];
  __shared__ __attribute__((aligned(16))) short Bs[3][128 * 32];
  const int t = threadIdx.x;
  const int lane = t & 63, w = t >> 6;
  const int wr = w >> 1, wc = w & 1;
  const int g = lane >> 4, r16 = lane & 15;
  const int m0 = blockIdx.y * 128, n0 = blockIdx.x * 128;

  int goffs[2], loffs[2];
#pragma unroll
  for (int p = 0; p < 2; ++p) {
    int c = p * 256 + t;
    int row = c >> 2, u = c & 3;
    goffs[p] = row * Kdim + ((u ^ ((row >> 1) & 3)) * 8);
    loffs[p] = c * 16;
  }
  const short* Abase = A + (size_t)m0 * Kdim;
  const short* Bbase = Bw + (size_t)n0 * Kdim;

  auto STAGE = [&](int s, int k0) {
#pragma unroll
    for (int p = 0; p < 2; ++p) {
      gload16(Abase + k0 + goffs[p], (char*)&As[s][0] + loffs[p]);
      gload16(Bbase + k0 + goffs[p], (char*)&Bs[s][0] + loffs[p]);
    }
  };

  f32x4 acc[4][4];
#pragma unroll
  for (int i = 0; i < 4; ++i)
#pragma unroll
    for (int j = 0; j < 4; ++j) acc[i][j] = (f32x4){0.f, 0.f, 0.f, 0.f};

  const int nsteps = Kdim >> 5;
  STAGE(0, 0);
  STAGE(1, 32);
  asm volatile("s_waitcnt vmcnt(4)" ::: "memory");
  __builtin_amdgcn_s_barrier();
  asm volatile("" ::: "memory");

  int cur = 0, pre = 2;
  const int rsw = (r16 >> 1) & 3;
  for (int st = 0; st < nsteps; ++st) {
    if (st + 2 < nsteps) STAGE(pre, (st + 2) << 5);
    short8v af[4], bf[4];
#pragma unroll
    for (int mi = 0; mi < 4; ++mi)
      af[mi] = *(const short8v*)&As[cur][(wr * 64 + mi * 16 + r16) * 32 +
                                         ((g ^ rsw) * 8)];
#pragma unroll
    for (int ni = 0; ni < 4; ++ni)
      bf[ni] = *(const short8v*)&Bs[cur][(wc * 64 + ni * 16 + r16) * 32 +
                                         ((g ^ rsw) * 8)];
#pragma unroll
    for (int mi = 0; mi < 4; ++mi)
#pragma unroll
      for (int ni = 0; ni < 4; ++ni)
        acc[mi][ni] = MFMA16(af[mi], bf[ni], acc[mi][ni]);
    if (st + 2 < nsteps) asm volatile("s_waitcnt vmcnt(4)" ::: "memory");
    else                 asm volatile("s_waitcnt vmcnt(0)" ::: "memory");
    __builtin_amdgcn_s_barrier();
    asm volatile("" ::: "memory");
    cur = (cur == 2) ? 0 : cur + 1;
    pre = (pre == 2) ? 0 : pre + 1;
  }

#pragma unroll
  for (int ni = 0; ni < 4; ++ni) {
    int col = n0 + wc * 64 + ni * 16 + r16;
    float bv = bias[col];
#pragma unroll
    for (int mi = 0; mi < 4; ++mi) {
      int mrow = m0 + wr * 64 + mi * 16 + g * 4;
#pragma unroll
      for (int r = 0; r < 4; ++r)
        fout[(size_t)(mrow + r) * Ndim + col] = acc[mi][ni][r] + bv;
    }
  }
}

// ---------------- causal flash attention (v5, r15-exact) -------------------
__global__ __launch_bounds__(512)
void fattn(const short* __restrict__ q, const short* __restrict__ k,
           const short* __restrict__ vT, const float2* __restrict__ tbl,
           short* __restrict__ o) {
  const int bx = blockIdx.x;
  const int idx = bx >> 6;
  const int qt = (idx < 4) ? (7 - idx) : (idx - 4);  // pairs sum to 7
  const int bh = bx & 63;
  const int b = bh >> 4, h = bh & 15;
  const int t = threadIdx.x, lane = t & 63, w = t >> 6;
  const int q32 = lane & 31, hi = lane >> 5;
  const int hi4 = hi * 4;

  __shared__ __attribute__((aligned(16))) short Ks[2][64 * 64];
  __shared__ __attribute__((aligned(16))) short Vt[2][64 * 64];

  const short* qb = q + (size_t)bh * 2048 * 64;
  const short* kb = k + (size_t)bh * 2048 * 64;
  const short* vb = vT + (size_t)bh * 2048 * 64;

  const int srow = t >> 3, su = t & 7;
  const int sx8 = (su ^ (srow & 7)) * 8;
  const int koff = srow * 64 + sx8;
  const int voff = srow * 2048 + sx8;
  const int loff = t * 16;
  auto STAGE = [&](int s, int kt) {
    gload16(kb + (size_t)kt * 4096 + koff, (char*)&Ks[s][0] + loff);
    gload16(vb + kt * 64 + voff, (char*)&Vt[s][0] + loff);
  };

  const int q0w = qt * 256 + w * 32;
  const int nrow = q0w + q32;

  const float sc = 0.125f * 1.44269504088896f;
  short8v aq[4];
#pragma unroll
  for (int ds = 0; ds < 4; ++ds) {
    short8v raw = *(const short8v*)(qb + (size_t)nrow * 64 + ds * 16 + hi * 8);
    short8v rq;
#pragma unroll
    for (int j = 0; j < 4; ++j) {
      float2 cs = tbl[nrow * 32 + ds * 8 + hi4 + j];
      float x0 = bf2f(raw[2 * j]), x1 = bf2f(raw[2 * j + 1]);
      rq[2 * j]     = f2bf((x0 * cs.x - x1 * cs.y) * sc);
      rq[2 * j + 1] = f2bf((x0 * cs.y + x1 * cs.x) * sc);
    }
    aq[ds] = rq;
  }

  const short one_bf = 0x3F80;
  const short8v ones = {one_bf, one_bf, one_bf, one_bf, one_bf, one_bf, one_bf, one_bf};
  const float M = 24.0f;

  f32x16 oacc[2], lacc;
#pragma unroll
  for (int j = 0; j < 16; ++j) { oacc[0][j] = 0.f; oacc[1][j] = 0.f; lacc[j] = 0.f; }

  const int ktmax = 4 * qt + 3;

  STAGE(0, 0);
  __syncthreads();

  for (int kt = 0; kt <= ktmax; ++kt) {
    const int cur = kt & 1;
    if (kt < ktmax) STAGE(cur ^ 1, kt + 1);

    if (kt * 64 <= q0w + 31) {
      f32x16 s[2];
#pragma unroll
      for (int j = 0; j < 16; ++j) { s[0][j] = 0.f; s[1][j] = 0.f; }
      __builtin_amdgcn_s_setprio(1);
#pragma unroll
      for (int ds = 0; ds < 4; ++ds) {
        int u = 2 * ds + hi;
#pragma unroll
        for (int kbl = 0; kbl < 2; ++kbl) {
          int key = kbl * 32 + q32;
          short8v kf = *(const short8v*)((const char*)&Ks[cur][0] + key * 128 +
                                         ((u ^ (key & 7)) << 4));
          s[kbl] = MFMA32(kf, aq[ds], s[kbl]);
        }
      }
      __builtin_amdgcn_s_setprio(0);

      const bool needmask = (kt * 64 + 63 > q0w);
      unsigned pa[4][4];
#pragma unroll
      for (int kbl = 0; kbl < 2; ++kbl) {
        if (needmask) {
#pragma unroll
          for (int r = 0; r < 16; ++r) {
            int keyg = kt * 64 + kbl * 32 + (r & 3) + 8 * (r >> 2) + hi4;
            if (keyg > nrow) s[kbl][r] = -1e30f;
          }
        }
        unsigned pk[8];
#pragma unroll
        for (int p = 0; p < 8; ++p) {
          float p0 = __builtin_amdgcn_exp2f(s[kbl][2 * p] - M);
          float p1 = __builtin_amdgcn_exp2f(s[kbl][2 * p + 1] - M);
          pk[p] = packbf(p0, p1);
        }
        {
          unsigned x0 = pk[0], x1 = pk[2];
          unsigned y0 = pk[1], y1 = pk[3];
          PLSWAP(x0, x1);
          PLSWAP(y0, y1);
          pa[kbl * 2][0] = x0; pa[kbl * 2][1] = y0;
          pa[kbl * 2][2] = x1; pa[kbl * 2][3] = y1;
        }
        {
          unsigned x0 = pk[4], x1 = pk[6];
          unsigned y0 = pk[5], y1 = pk[7];
          PLSWAP(x0, x1);
          PLSWAP(y0, y1);
          pa[kbl * 2 + 1][0] = x0; pa[kbl * 2 + 1][1] = y0;
          pa[kbl * 2 + 1][2] = x1; pa[kbl * 2 + 1][3] = y1;
        }
      }

      __builtin_amdgcn_s_setprio(1);
#pragma unroll
      for (int kk = 0; kk < 4; ++kk) {
        short8v paf = __builtin_bit_cast(
            short8v, (u32x4){pa[kk][0], pa[kk][1], pa[kk][2], pa[kk][3]});
        lacc = MFMA32(paf, ones, lacc);
        int u = 2 * kk + hi;
#pragma unroll
        for (int db = 0; db < 2; ++db) {
          int d = db * 32 + q32;
          short8v vf = *(const short8v*)((const char*)&Vt[cur][0] + d * 128 +
                                         ((u ^ (d & 7)) << 4));
          oacc[db] = MFMA32(paf, vf, oacc[db]);
        }
      }
      __builtin_amdgcn_s_setprio(0);
    }
    __syncthreads();
  }

#pragma unroll
  for (int r = 0; r < 16; ++r) {
    float ilr = 1.f / lacc[r];
    int qg = q0w + (r & 3) + 8 * (r >> 2) + hi4;
    short* orow = o + ((size_t)(b * 2048 + qg)) * 1024 + h * 64;
    orow[q32]      = f2bf(oacc[0][r] * ilr);
    orow[32 + q32] = f2bf(oacc[1][r] * ilr);
  }
}

// ---------------- launcher ----------------
extern "C" void kernel_launch(void* const* d_in, const int* in_sizes, int n_in,
                              void* d_out, int out_size, void* d_ws, size_t ws_size,
                              hipStream_t stream) {
  const float* x    = (const float*)d_in[0];
  const float* Wqkv = (const float*)d_in[1];
  const float* bqkv = (const float*)d_in[2];
  const float* Wout = (const float*)d_in[3];
  const float* bout = (const float*)d_in[4];

  char* p = (char*)d_ws;
  short* xb = (short*)p;    p += (size_t)8192 * 1024 * 2;   // x bf16; reused as attn output
  short* wqkvb = (short*)p; p += (size_t)3072 * 1024 * 2;
  short* woutb = (short*)p; p += (size_t)1024 * 1024 * 2;
  short* qbf = (short*)p;   p += (size_t)64 * 2048 * 64 * 2;
  short* kbf = (short*)p;   p += (size_t)64 * 2048 * 64 * 2;
  short* vbf = (short*)p;   p += (size_t)64 * 2048 * 64 * 2;  // vT (BH, D, N)
  float2* tbl = (float2*)p; p += (size_t)2048 * 32 * 8;

  cvt_all<<<12288, 256, 0, stream>>>(x, Wqkv, Wout, xb, wqkvb, woutb);
  rope_table<<<256, 256, 0, stream>>>(tbl);

  gemm256<<<dim3(12, 32), 512, 0, stream>>>(xb, wqkvb, bqkv, qbf, kbf, vbf, 1024);
  rope_k<<<4096, 256, 0, stream>>>(kbf, tbl);
  fattn<<<dim3(512), 512, 0, stream>>>(qbf, kbf, vbf, tbl, xb);
  gemm_f32<<<dim3(8, 64), 256, 0, stream>>>(xb, woutb, bout, (float*)d_out, 1024, 1024);
}